// Round 9
// baseline (79.941 us; speedup 1.0000x reference)
//
#include <hip/hip_runtime.h>
#include <hip/hip_fp16.h>

#define Hh 512
#define Ww 512
#define Bb 2
#define Gg 4
#define Ff 9
#define Cc 3
#define Nn (Hh*Ww)

#define TILE 32
#define RS 36          // fM region: tile + halo 2
#define RSP 37         // padded row stride
#define DS 34          // dinv region: tile + halo 1
#define DSP 35         // padded row stride
#define NT 256         // each thread owns a 2x2 pixel quad

typedef float f32x2 __attribute__((ext_vector_type(2)));

struct Fm8 { unsigned a, b; float cf; };   // 8 fp8 e4m3 + f8 (fp16-decoded)

__device__ __forceinline__ float dot8(const Fm8& p, const Fm8& q) {
    f32x2 p01 = __builtin_amdgcn_cvt_pk_f32_fp8(p.a, false);
    f32x2 p23 = __builtin_amdgcn_cvt_pk_f32_fp8(p.a, true);
    f32x2 p45 = __builtin_amdgcn_cvt_pk_f32_fp8(p.b, false);
    f32x2 p67 = __builtin_amdgcn_cvt_pk_f32_fp8(p.b, true);
    f32x2 q01 = __builtin_amdgcn_cvt_pk_f32_fp8(q.a, false);
    f32x2 q23 = __builtin_amdgcn_cvt_pk_f32_fp8(q.a, true);
    f32x2 q45 = __builtin_amdgcn_cvt_pk_f32_fp8(q.b, false);
    f32x2 q67 = __builtin_amdgcn_cvt_pk_f32_fp8(q.b, true);
    float s = p01[0] * q01[0];
    s = fmaf(p01[1], q01[1], s);
    s = fmaf(p23[0], q23[0], s);
    s = fmaf(p23[1], q23[1], s);
    s = fmaf(p45[0], q45[0], s);
    s = fmaf(p45[1], q45[1], s);
    s = fmaf(p67[0], q67[0], s);
    s = fmaf(p67[1], q67[1], s);
    s = fmaf(p.cf, q.cf, s);
    return s;
}

__device__ __forceinline__ float ew_of(float s) {
    s = fminf(fmaxf(s, -10.f), 10.f);
    return __expf(s);
}

__global__ void __launch_bounds__(NT, 8) fused_kernel(const float* __restrict__ img,
                                                      const float* __restrict__ M,
                                                      const float* __restrict__ sig,
                                                      float* __restrict__ out) {
    __shared__ uint2   fm8[RS * RSP];      // 8 fp8/px
    __shared__ __half  fmC[RS * RSP];      // f8
    __shared__ float   dv[DS * DSP];       // 1/sqrt(deg); 1.0 in OOB slots

    const int tid = threadIdx.x;
    // XCD-plane swizzle: XCD i owns plane i; tiles sequential -> halo reuse in L2.
    const int bg   = blockIdx.x & 7;            // b*G+g
    const int tile = blockIdx.x >> 3;           // 0..255
    const int g    = bg & (Gg - 1);
    const int by0  = (tile >> 4) * TILE;
    const int bx0  = (tile & 15) * TILE;
    const bool border = (by0 == 0) | (by0 == Hh - TILE) | (bx0 == 0) | (bx0 == Ww - TILE);

    const float* imgP = img + (size_t)bg * Ff * Nn;
    const float* sgp  = sig + (size_t)bg * Cc * Nn;
    const float* Mg   = M + g * Ff * Ff;        // block-uniform -> scalar path

    auto LD = [&](int idx) -> Fm8 {
        Fm8 p;
        uint2 w = fm8[idx];
        p.a = w.x; p.b = w.y;
        p.cf = __half2float(fmC[idx]);
        return p;
    };

    // ---- Phase 1: fm for 36x36 halo-2 region, fp8-packed, OOB -> 0 ----
    for (int i = tid; i < RS * RS; i += NT) {
        unsigned r = (unsigned)i / RS, c = (unsigned)i - r * RS;
        int gy = by0 - 2 + (int)r, gx = bx0 - 2 + (int)c;
        float m[Ff];
        if ((unsigned)gy < Hh && (unsigned)gx < Ww) {
            const float* src = imgP + gy * Ww + gx;
            float v[Ff]; float ss = 0.f;
#pragma unroll
            for (int f = 0; f < Ff; ++f) { v[f] = src[f * Nn]; ss += v[f] * v[f]; }
            float inv = 1.0f / fmaxf(sqrtf(ss), 1e-12f);
#pragma unroll
            for (int f = 0; f < Ff; ++f) v[f] *= inv;
#pragma unroll
            for (int vv = 0; vv < Ff; ++vv) {
                float acc = 0.f;
#pragma unroll
                for (int cc = 0; cc < Ff; ++cc) acc = fmaf(v[cc], Mg[cc * Ff + vv], acc);
                m[vv] = acc;
            }
        } else {
#pragma unroll
            for (int f = 0; f < Ff; ++f) m[f] = 0.f;
        }
        int si = r * RSP + c;
        int A = __builtin_amdgcn_cvt_pk_fp8_f32(m[0], m[1], 0, false);
        A     = __builtin_amdgcn_cvt_pk_fp8_f32(m[2], m[3], A, true);
        int Bw = __builtin_amdgcn_cvt_pk_fp8_f32(m[4], m[5], 0, false);
        Bw     = __builtin_amdgcn_cvt_pk_fp8_f32(m[6], m[7], Bw, true);
        fm8[si] = make_uint2((unsigned)A, (unsigned)Bw);
        fmC[si] = __float2half_rn(m[8]);
    }
    __syncthreads();

    // ---- Phase 2a: 2x2 quad per thread: 30 unique dots (6 shared), deg->dinv ----
    const int r2 = tid >> 4, c2 = tid & 15;
    const int gy0 = by0 + 2 * r2, gx0 = bx0 + 2 * c2;
    const int wb  = (2 * r2 + 1) * RSP + (2 * c2 + 1);   // fm idx of window (0,0)

    Fm8 w0[4], w1[4], w2[4], w3[4];
#pragma unroll
    for (int ci = 0; ci < 4; ++ci) w0[ci] = LD(wb + ci);
#pragma unroll
    for (int ci = 0; ci < 4; ++ci) w1[ci] = LD(wb + RSP + ci);
#pragma unroll
    for (int ci = 0; ci < 4; ++ci) w2[ci] = LD(wb + 2 * RSP + ci);

    float e0[9], e1[9], e2[9], e3[9];
    // px0 = w1[1]
    e0[0] = ew_of(dot8(w1[1], w0[0])); e0[1] = ew_of(dot8(w1[1], w0[1])); e0[2] = ew_of(dot8(w1[1], w0[2]));
    e0[3] = ew_of(dot8(w1[1], w1[0])); e0[4] = ew_of(dot8(w1[1], w1[1])); e0[5] = ew_of(dot8(w1[1], w1[2]));
    e0[6] = ew_of(dot8(w1[1], w2[0])); e0[7] = ew_of(dot8(w1[1], w2[1])); e0[8] = ew_of(dot8(w1[1], w2[2]));
    // px1 = w1[2]  (shares W-edge with px0)
    e1[0] = ew_of(dot8(w1[2], w0[1])); e1[1] = ew_of(dot8(w1[2], w0[2])); e1[2] = ew_of(dot8(w1[2], w0[3]));
    e1[3] = e0[5];                     e1[4] = ew_of(dot8(w1[2], w1[2])); e1[5] = ew_of(dot8(w1[2], w1[3]));
    e1[6] = ew_of(dot8(w1[2], w2[1])); e1[7] = ew_of(dot8(w1[2], w2[2])); e1[8] = ew_of(dot8(w1[2], w2[3]));

#pragma unroll
    for (int ci = 0; ci < 4; ++ci) w3[ci] = LD(wb + 3 * RSP + ci);   // w0 now dead

    // px2 = w2[1]  (shares N=e0.S, NE=e1.SW)
    e2[0] = ew_of(dot8(w2[1], w1[0])); e2[1] = e0[7];                     e2[2] = e1[6];
    e2[3] = ew_of(dot8(w2[1], w2[0])); e2[4] = ew_of(dot8(w2[1], w2[1])); e2[5] = ew_of(dot8(w2[1], w2[2]));
    e2[6] = ew_of(dot8(w2[1], w3[0])); e2[7] = ew_of(dot8(w2[1], w3[1])); e2[8] = ew_of(dot8(w2[1], w3[2]));
    // px3 = w2[2]  (shares NW=e0.SE, N=e1.S, W=e2.E)
    e3[0] = e0[8];                     e3[1] = e1[7];                     e3[2] = ew_of(dot8(w2[2], w1[3]));
    e3[3] = e2[5];                     e3[4] = ew_of(dot8(w2[2], w2[2])); e3[5] = ew_of(dot8(w2[2], w2[3]));
    e3[6] = ew_of(dot8(w2[2], w3[1])); e3[7] = ew_of(dot8(w2[2], w3[2])); e3[8] = ew_of(dot8(w2[2], w3[3]));

    if (border) {   // mask edges leaving the image
#pragma unroll
        for (int j = 0; j < 9; ++j) {
            int dy = j / 3 - 1, dx = j % 3 - 1;
            if (!(((unsigned)(gy0 + dy)     < Hh) & ((unsigned)(gx0 + dx)     < Ww))) e0[j] = 0.f;
            if (!(((unsigned)(gy0 + dy)     < Hh) & ((unsigned)(gx0 + 1 + dx) < Ww))) e1[j] = 0.f;
            if (!(((unsigned)(gy0 + 1 + dy) < Hh) & ((unsigned)(gx0 + dx)     < Ww))) e2[j] = 0.f;
            if (!(((unsigned)(gy0 + 1 + dy) < Hh) & ((unsigned)(gx0 + 1 + dx) < Ww))) e3[j] = 0.f;
        }
    }

    float deg0 = 0.f, deg1 = 0.f, deg2 = 0.f, deg3 = 0.f;
#pragma unroll
    for (int j = 0; j < 9; ++j) { deg0 += e0[j]; deg1 += e1[j]; deg2 += e2[j]; deg3 += e3[j]; }
    {
        const int db = (2 * r2 + 1) * DSP + (2 * c2 + 1);
        dv[db]           = 1.0f / sqrtf(deg0);
        dv[db + 1]       = 1.0f / sqrtf(deg1);
        dv[db + DSP]     = 1.0f / sqrtf(deg2);
        dv[db + DSP + 1] = 1.0f / sqrtf(deg3);
    }

    // ---- Phase 2b: halo ring (132 px): deg only; OOB slots -> 1.0 ----
    if (tid < 132) {
        int r, c;
        if (tid < 34)       { r = 0;        c = tid;       }
        else if (tid < 68)  { r = 33;       c = tid - 34;  }
        else if (tid < 100) { r = tid - 67; c = 0;         }
        else                { r = tid - 99; c = 33;        }
        int gy = by0 - 1 + r, gx = bx0 - 1 + c;
        float d = 1.0f;
        if ((unsigned)gy < Hh && (unsigned)gx < Ww) {
            int fi = (r + 1) * RSP + (c + 1);
            Fm8 a = LD(fi);
            float deg = 0.f;
#pragma unroll
            for (int j = 0; j < 9; ++j) {
                int dy = j / 3 - 1, dx = j % 3 - 1;
                Fm8 q = LD(fi + dy * RSP + dx);
                float e = ew_of(dot8(a, q));
                bool valid = ((unsigned)(gy + dy) < Hh) & ((unsigned)(gx + dx) < Ww);
                deg += valid ? e : 0.f;
            }
            d = 1.0f / sqrtf(deg);
        }
        dv[r * DSP + c] = d;
    }
    __syncthreads();

    // ---- Phase 3: e -> w in regs; sig 4x4 window from global (L2-hot) ----
    float dvf[16];
    {
        const int db = 2 * r2 * DSP + 2 * c2;    // window (0,0) in dv coords
#pragma unroll
        for (int k = 0; k < 16; ++k)
            dvf[k] = dv[db + (k >> 2) * DSP + (k & 3)];
    }
    const float dp0 = dvf[5], dp1 = dvf[6], dp2 = dvf[9], dp3 = dvf[10];
#pragma unroll
    for (int j = 0; j < 9; ++j) {
        const int k0 = (j / 3) * 4 + (j % 3);
        e0[j] = dp0 * e0[j] * dvf[k0];
        e1[j] = dp1 * e1[j] * dvf[k0 + 1];
        e2[j] = dp2 * e2[j] * dvf[k0 + 4];
        e3[j] = dp3 * e3[j] * dvf[k0 + 5];
    }

    int ry[4], cx[4];
#pragma unroll
    for (int i = 0; i < 4; ++i) {
        ry[i] = min(max(gy0 - 1 + i, 0), Hh - 1) * Ww;   // clamped (w==0 kills OOB)
        cx[i] = min(max(gx0 - 1 + i, 0), Ww - 1);
    }

    float* o = out + (size_t)bg * Cc * Nn;
    const int p = gy0 * Ww + gx0;
#pragma unroll
    for (int ch = 0; ch < Cc; ++ch) {
        const float* sc = sgp + (size_t)ch * Nn;
        float s[16];
#pragma unroll
        for (int k = 0; k < 16; ++k) s[k] = sc[ry[k >> 2] + cx[k & 3]];
        float a0 = 0.f, a1 = 0.f, a2 = 0.f, a3 = 0.f;
#pragma unroll
        for (int j = 0; j < 9; ++j) {
            const int k0 = (j / 3) * 4 + (j % 3);
            a0 = fmaf(e0[j], s[k0],     a0);
            a1 = fmaf(e1[j], s[k0 + 1], a1);
            a2 = fmaf(e2[j], s[k0 + 4], a2);
            a3 = fmaf(e3[j], s[k0 + 5], a3);
        }
        float* oc = o + (size_t)ch * Nn;
        *(float2*)&oc[p]      = make_float2(s[5] - a0, s[6]  - a1);
        *(float2*)&oc[p + Ww] = make_float2(s[9] - a2, s[10] - a3);
    }
}

extern "C" void kernel_launch(void* const* d_in, const int* in_sizes, int n_in,
                              void* d_out, int out_size, void* d_ws, size_t ws_size,
                              hipStream_t stream) {
    const float* img = (const float*)d_in[0];   // (B,G,F,H,W)
    const float* sig = (const float*)d_in[1];   // (B,G,C,H,W)
    const float* M   = (const float*)d_in[2];   // (G,F,F)
    float* out = (float*)d_out;

    fused_kernel<<<dim3(256 * Bb * Gg), NT, 0, stream>>>(img, M, sig, out);
}

// Round 10
// 38.619 us; speedup vs baseline: 2.0700x; 2.0700x over previous
//
#include <hip/hip_runtime.h>
#include <hip/hip_fp16.h>

#define Hh 512
#define Ww 512
#define Bb 2
#define Gg 4
#define Ff 9
#define Cc 3
#define Nn (Hh*Ww)

#define TILE 32
#define RS 36          // fM region: tile + halo 2
#define RSP 37         // padded row stride
#define DS 34          // dinv region: tile + halo 1
#define DSP 35         // padded row stride
#define NT 256         // each thread owns a 2x2 pixel quad

typedef float f32x2 __attribute__((ext_vector_type(2)));

struct Fm8 { unsigned a, b; float cf; };   // 8 fp8 e4m3 + f8 (fp16-decoded)

__device__ __forceinline__ float dot8(const Fm8& p, const Fm8& q) {
    f32x2 p01 = __builtin_amdgcn_cvt_pk_f32_fp8(p.a, false);
    f32x2 p23 = __builtin_amdgcn_cvt_pk_f32_fp8(p.a, true);
    f32x2 p45 = __builtin_amdgcn_cvt_pk_f32_fp8(p.b, false);
    f32x2 p67 = __builtin_amdgcn_cvt_pk_f32_fp8(p.b, true);
    f32x2 q01 = __builtin_amdgcn_cvt_pk_f32_fp8(q.a, false);
    f32x2 q23 = __builtin_amdgcn_cvt_pk_f32_fp8(q.a, true);
    f32x2 q45 = __builtin_amdgcn_cvt_pk_f32_fp8(q.b, false);
    f32x2 q67 = __builtin_amdgcn_cvt_pk_f32_fp8(q.b, true);
    float s = p01[0] * q01[0];
    s = fmaf(p01[1], q01[1], s);
    s = fmaf(p23[0], q23[0], s);
    s = fmaf(p23[1], q23[1], s);
    s = fmaf(p45[0], q45[0], s);
    s = fmaf(p45[1], q45[1], s);
    s = fmaf(p67[0], q67[0], s);
    s = fmaf(p67[1], q67[1], s);
    s = fmaf(p.cf, q.cf, s);
    return s;
}

__device__ __forceinline__ float ew_of(float s) {
    s = fminf(fmaxf(s, -10.f), 10.f);
    return __expf(s);
}

__global__ void __launch_bounds__(NT, 6) fused_kernel(const float* __restrict__ img,
                                                      const float* __restrict__ M,
                                                      const float* __restrict__ sig,
                                                      float* __restrict__ out) {
    __shared__ uint2   fm8[RS * RSP];      // 8 fp8/px
    __shared__ __half  fmC[RS * RSP];      // f8
    __shared__ float   dv[DS * DSP];       // 1/sqrt(deg); 1.0 in OOB slots

    const int tid = threadIdx.x;
    // XCD-plane swizzle: XCD i owns plane i; tiles sequential -> halo reuse in L2.
    const int bg   = blockIdx.x & 7;            // b*G+g
    const int tile = blockIdx.x >> 3;           // 0..255
    const int g    = bg & (Gg - 1);
    const int by0  = (tile >> 4) * TILE;
    const int bx0  = (tile & 15) * TILE;
    const bool border = (by0 == 0) | (by0 == Hh - TILE) | (bx0 == 0) | (bx0 == Ww - TILE);

    const float* imgP = img + (size_t)bg * Ff * Nn;
    const float* sgp  = sig + (size_t)bg * Cc * Nn;
    const float* Mg   = M + g * Ff * Ff;        // block-uniform -> scalar path

    auto LD = [&](int idx) -> Fm8 {
        Fm8 p;
        uint2 w = fm8[idx];
        p.a = w.x; p.b = w.y;
        p.cf = __half2float(fmC[idx]);
        return p;
    };

    // ---- Phase 1: fm for 36x36 halo-2 region, fp8-packed, OOB -> 0 ----
    for (int i = tid; i < RS * RS; i += NT) {
        unsigned r = (unsigned)i / RS, c = (unsigned)i - r * RS;
        int gy = by0 - 2 + (int)r, gx = bx0 - 2 + (int)c;
        float m[Ff];
        if ((unsigned)gy < Hh && (unsigned)gx < Ww) {
            const float* src = imgP + gy * Ww + gx;
            float v[Ff]; float ss = 0.f;
#pragma unroll
            for (int f = 0; f < Ff; ++f) { v[f] = src[f * Nn]; ss += v[f] * v[f]; }
            float inv = 1.0f / fmaxf(sqrtf(ss), 1e-12f);
#pragma unroll
            for (int f = 0; f < Ff; ++f) v[f] *= inv;
#pragma unroll
            for (int vv = 0; vv < Ff; ++vv) {
                float acc = 0.f;
#pragma unroll
                for (int cc = 0; cc < Ff; ++cc) acc = fmaf(v[cc], Mg[cc * Ff + vv], acc);
                m[vv] = acc;
            }
        } else {
#pragma unroll
            for (int f = 0; f < Ff; ++f) m[f] = 0.f;
        }
        int si = r * RSP + c;
        int A = __builtin_amdgcn_cvt_pk_fp8_f32(m[0], m[1], 0, false);
        A     = __builtin_amdgcn_cvt_pk_fp8_f32(m[2], m[3], A, true);
        int Bw = __builtin_amdgcn_cvt_pk_fp8_f32(m[4], m[5], 0, false);
        Bw     = __builtin_amdgcn_cvt_pk_fp8_f32(m[6], m[7], Bw, true);
        fm8[si] = make_uint2((unsigned)A, (unsigned)Bw);
        fmC[si] = __float2half_rn(m[8]);
    }
    __syncthreads();

    // ---- Phase 2a: 2x2 quad per thread: 30 unique dots (6 shared), deg->dinv ----
    const int r2 = tid >> 4, c2 = tid & 15;
    const int gy0 = by0 + 2 * r2, gx0 = bx0 + 2 * c2;
    const int wb  = (2 * r2 + 1) * RSP + (2 * c2 + 1);   // fm idx of window (0,0)

    Fm8 w0[4], w1[4], w2[4], w3[4];
#pragma unroll
    for (int ci = 0; ci < 4; ++ci) w0[ci] = LD(wb + ci);
#pragma unroll
    for (int ci = 0; ci < 4; ++ci) w1[ci] = LD(wb + RSP + ci);
#pragma unroll
    for (int ci = 0; ci < 4; ++ci) w2[ci] = LD(wb + 2 * RSP + ci);

    float e0[9], e1[9], e2[9], e3[9];
    // px0 = w1[1]
    e0[0] = ew_of(dot8(w1[1], w0[0])); e0[1] = ew_of(dot8(w1[1], w0[1])); e0[2] = ew_of(dot8(w1[1], w0[2]));
    e0[3] = ew_of(dot8(w1[1], w1[0])); e0[4] = ew_of(dot8(w1[1], w1[1])); e0[5] = ew_of(dot8(w1[1], w1[2]));
    e0[6] = ew_of(dot8(w1[1], w2[0])); e0[7] = ew_of(dot8(w1[1], w2[1])); e0[8] = ew_of(dot8(w1[1], w2[2]));
    // px1 = w1[2]  (shares W-edge with px0)
    e1[0] = ew_of(dot8(w1[2], w0[1])); e1[1] = ew_of(dot8(w1[2], w0[2])); e1[2] = ew_of(dot8(w1[2], w0[3]));
    e1[3] = e0[5];                     e1[4] = ew_of(dot8(w1[2], w1[2])); e1[5] = ew_of(dot8(w1[2], w1[3]));
    e1[6] = ew_of(dot8(w1[2], w2[1])); e1[7] = ew_of(dot8(w1[2], w2[2])); e1[8] = ew_of(dot8(w1[2], w2[3]));

#pragma unroll
    for (int ci = 0; ci < 4; ++ci) w3[ci] = LD(wb + 3 * RSP + ci);   // w0 now dead

    // px2 = w2[1]  (shares N=e0.S, NE=e1.SW)
    e2[0] = ew_of(dot8(w2[1], w1[0])); e2[1] = e0[7];                     e2[2] = e1[6];
    e2[3] = ew_of(dot8(w2[1], w2[0])); e2[4] = ew_of(dot8(w2[1], w2[1])); e2[5] = ew_of(dot8(w2[1], w2[2]));
    e2[6] = ew_of(dot8(w2[1], w3[0])); e2[7] = ew_of(dot8(w2[1], w3[1])); e2[8] = ew_of(dot8(w2[1], w3[2]));
    // px3 = w2[2]  (shares NW=e0.SE, N=e1.S, W=e2.E)
    e3[0] = e0[8];                     e3[1] = e1[7];                     e3[2] = ew_of(dot8(w2[2], w1[3]));
    e3[3] = e2[5];                     e3[4] = ew_of(dot8(w2[2], w2[2])); e3[5] = ew_of(dot8(w2[2], w2[3]));
    e3[6] = ew_of(dot8(w2[2], w3[1])); e3[7] = ew_of(dot8(w2[2], w3[2])); e3[8] = ew_of(dot8(w2[2], w3[3]));

    if (border) {   // mask edges leaving the image
#pragma unroll
        for (int j = 0; j < 9; ++j) {
            int dy = j / 3 - 1, dx = j % 3 - 1;
            if (!(((unsigned)(gy0 + dy)     < Hh) & ((unsigned)(gx0 + dx)     < Ww))) e0[j] = 0.f;
            if (!(((unsigned)(gy0 + dy)     < Hh) & ((unsigned)(gx0 + 1 + dx) < Ww))) e1[j] = 0.f;
            if (!(((unsigned)(gy0 + 1 + dy) < Hh) & ((unsigned)(gx0 + dx)     < Ww))) e2[j] = 0.f;
            if (!(((unsigned)(gy0 + 1 + dy) < Hh) & ((unsigned)(gx0 + 1 + dx) < Ww))) e3[j] = 0.f;
        }
    }

    float deg0 = 0.f, deg1 = 0.f, deg2 = 0.f, deg3 = 0.f;
#pragma unroll
    for (int j = 0; j < 9; ++j) { deg0 += e0[j]; deg1 += e1[j]; deg2 += e2[j]; deg3 += e3[j]; }
    {
        const int db = (2 * r2 + 1) * DSP + (2 * c2 + 1);
        dv[db]           = 1.0f / sqrtf(deg0);
        dv[db + 1]       = 1.0f / sqrtf(deg1);
        dv[db + DSP]     = 1.0f / sqrtf(deg2);
        dv[db + DSP + 1] = 1.0f / sqrtf(deg3);
    }

    // ---- Phase 2b: halo ring (132 px): deg only; OOB slots -> 1.0 ----
    if (tid < 132) {
        int r, c;
        if (tid < 34)       { r = 0;        c = tid;       }
        else if (tid < 68)  { r = 33;       c = tid - 34;  }
        else if (tid < 100) { r = tid - 67; c = 0;         }
        else                { r = tid - 99; c = 33;        }
        int gy = by0 - 1 + r, gx = bx0 - 1 + c;
        float d = 1.0f;
        if ((unsigned)gy < Hh && (unsigned)gx < Ww) {
            int fi = (r + 1) * RSP + (c + 1);
            Fm8 a = LD(fi);
            float deg = 0.f;
#pragma unroll
            for (int j = 0; j < 9; ++j) {
                int dy = j / 3 - 1, dx = j % 3 - 1;
                Fm8 q = LD(fi + dy * RSP + dx);
                float e = ew_of(dot8(a, q));
                bool valid = ((unsigned)(gy + dy) < Hh) & ((unsigned)(gx + dx) < Ww);
                deg += valid ? e : 0.f;
            }
            d = 1.0f / sqrtf(deg);
        }
        dv[r * DSP + c] = d;
    }
    __syncthreads();

    // ---- Phase 3: e -> w in regs; sig 4x4 window from global (L2-hot) ----
    float dvf[16];
    {
        const int db = 2 * r2 * DSP + 2 * c2;    // window (0,0) in dv coords
#pragma unroll
        for (int k = 0; k < 16; ++k)
            dvf[k] = dv[db + (k >> 2) * DSP + (k & 3)];
    }
    const float dp0 = dvf[5], dp1 = dvf[6], dp2 = dvf[9], dp3 = dvf[10];
#pragma unroll
    for (int j = 0; j < 9; ++j) {
        const int k0 = (j / 3) * 4 + (j % 3);
        e0[j] = dp0 * e0[j] * dvf[k0];
        e1[j] = dp1 * e1[j] * dvf[k0 + 1];
        e2[j] = dp2 * e2[j] * dvf[k0 + 4];
        e3[j] = dp3 * e3[j] * dvf[k0 + 5];
    }

    int ry[4], cx[4];
#pragma unroll
    for (int i = 0; i < 4; ++i) {
        ry[i] = min(max(gy0 - 1 + i, 0), Hh - 1) * Ww;   // clamped (w==0 kills OOB)
        cx[i] = min(max(gx0 - 1 + i, 0), Ww - 1);
    }

    float* o = out + (size_t)bg * Cc * Nn;
    const int p = gy0 * Ww + gx0;
#pragma unroll
    for (int ch = 0; ch < Cc; ++ch) {
        const float* sc = sgp + (size_t)ch * Nn;
        float s[16];
#pragma unroll
        for (int k = 0; k < 16; ++k) s[k] = sc[ry[k >> 2] + cx[k & 3]];
        float a0 = 0.f, a1 = 0.f, a2 = 0.f, a3 = 0.f;
#pragma unroll
        for (int j = 0; j < 9; ++j) {
            const int k0 = (j / 3) * 4 + (j % 3);
            a0 = fmaf(e0[j], s[k0],     a0);
            a1 = fmaf(e1[j], s[k0 + 1], a1);
            a2 = fmaf(e2[j], s[k0 + 4], a2);
            a3 = fmaf(e3[j], s[k0 + 5], a3);
        }
        float* oc = o + (size_t)ch * Nn;
        *(float2*)&oc[p]      = make_float2(s[5] - a0, s[6]  - a1);
        *(float2*)&oc[p + Ww] = make_float2(s[9] - a2, s[10] - a3);
    }
}

extern "C" void kernel_launch(void* const* d_in, const int* in_sizes, int n_in,
                              void* d_out, int out_size, void* d_ws, size_t ws_size,
                              hipStream_t stream) {
    const float* img = (const float*)d_in[0];   // (B,G,F,H,W)
    const float* sig = (const float*)d_in[1];   // (B,G,C,H,W)
    const float* M   = (const float*)d_in[2];   // (G,F,F)
    float* out = (float*)d_out;

    fused_kernel<<<dim3(256 * Bb * Gg), NT, 0, stream>>>(img, M, sig, out);
}